// Round 1
// baseline (2086.982 us; speedup 1.0000x reference)
//
#include <hip/hip_runtime.h>
#include <cfloat>
#include <math.h>

#define NOBS   256
#define NY     50
#define NX     30
#define NITER  400
#define LRATE  0.05f
#define CSTR   260     // ep_t column stride (floats); 260%4==0 keeps float4 LDS loads 16B-aligned
#define THRANK 40      // theta tracks the rank-40 KEY -> C = 41 every valid iter (stable)

__device__ __forceinline__ float rl_f(float x, int k) {
  // v_readlane: SGPR broadcast, no DS-pipe traffic (k may be a uniform variable -> SGPR index)
  return __int_as_float(__builtin_amdgcn_readlane(__float_as_int(x), k));
}
__device__ __forceinline__ unsigned long long rl_u64(unsigned long long x, int k) {
  const unsigned lo = (unsigned)__builtin_amdgcn_readlane((int)(unsigned)(x & 0xffffffffull), k);
  const unsigned hi = (unsigned)__builtin_amdgcn_readlane((int)(unsigned)(x >> 32), k);
  return ((unsigned long long)hi << 32) | lo;
}

// wave64 max: row_shr 1,2,4,8 + row_bcast 15,31; old=x keeps semantics identical to prior kernel.
#define DPP_MAXSTEP(x, ctrl)                                                       \
  x = fmaxf(x, __int_as_float(__builtin_amdgcn_update_dpp(                         \
        __float_as_int(x), __float_as_int(x), (ctrl), 0xF, 0xF, false)))

// RESTRUCTURE (R-this): 256 threads (4 waves, 1 wave/SIMD), ONE obs per thread, TWO barriers/iter.
// Prior 512-thread/6-barrier version was latency-bound: ~11.5k cyc/iter vs ~1.8k VALU-issue.
// All cross-half LDS exchanges (pex/cex/red8 + 2 counter barriers) replaced by thread-local state:
//   er[50] = full residual row (fwd dot local), epb[64] = full bwd slice (coef via in-wave readlane),
//   projection runs full 50-dim in-wave. Exchanges left: candidate keys + {max,ties,counts} (B1),
//   backward per-wave partials red4 (B2).
__global__ __launch_bounds__(256, 1)
void dro_kernel(
    const float* __restrict__ X, const float* __restrict__ Y,
    const float* __restrict__ W, const float* __restrict__ Bb,
    const float* __restrict__ DLT, const float* __restrict__ GMM,
    float* __restrict__ out)
{
  __shared__ __align__(16) float ep_t[51 * CSTR];          // init staging (dead after epb load)
  __shared__ __align__(16) unsigned long long rrk[NOBS];   // full keys (fallback scan)
  __shared__ __align__(16) unsigned long long ckey[128];   // 4 segments of 32 slots (quarter wsc)
  __shared__ __align__(16) float red4[4 * 64];             // per-wave backward partials
  __shared__ __align__(16) float wmax4[4];                 // per-wave max
  __shared__ __align__(16) int   ccnt4[4];                 // per-wave candidate count
  __shared__ __align__(16) int   wtie4[4];                 // per-wave max-tie count
  __shared__ unsigned long long th_key;

  const int tid  = threadIdx.x;     // 0..255 == owned observation
  const int lane = tid & 63;
  const int wsc  = tid >> 6;        // wave = obs quarter, obs base wsc*64
  const int t    = blockIdx.x;      // scenario

  const float delta = DLT[0];
  const float gamma = GMM[0];
  const float a     = fminf(delta * 0.5f, 255.0f / 256.0f);
  const float a256  = a * 256.0f;

  // ---- init: FULL residual row of owned obs in registers; stage ep column-major for epb ----
  float er[NY];
  {
    float xr[NX];
    #pragma unroll
    for (int k = 0; k < NX; ++k) xr[k] = X[tid * NX + k];
    #pragma unroll
    for (int j = 0; j < NY; ++j) {                 // W/B wave-uniform -> scalar loads
      float acc = Bb[j];
      #pragma unroll
      for (int k = 0; k < NX; ++k) acc = fmaf(xr[k], W[j * NX + k], acc);
      const float e = Y[tid * NY + j] - acc;
      er[j] = e;
      ep_t[j * CSTR + tid] = e;                    // column-major
    }
    ep_t[NY * CSTR + tid] = 1.0f;                  // ones column -> c gradient
  }
  float yhl;                                       // y_hat row t, per-lane copy
  {
    const int jr = (lane < NY) ? lane : 0;
    float acc = Bb[jr];
    #pragma unroll
    for (int k = 0; k < NX; ++k) acc = fmaf(X[t * NX + k], W[jr * NX + k], acc);
    yhl = acc;
    if (tid < NY) out[NOBS * NY + t * NY + tid] = acc;
  }
  if (tid == 0) th_key = ~0ull;                    // iter 0: all candidates -> exact fallback
  __syncthreads();

  // epb: iteration-invariant backward slice in REGISTERS.
  // Lane l: column min(l,50), obs [wsc*64, wsc*64+64). coef of obs wsc*64+q lives in lane q
  // of the SAME wave -> backward is pure in-wave readlane, zero DS reads.
  float epb[64];
  {
    const int colc = (lane < 51) ? lane : 50;
    const float* eb = &ep_t[colc * CSTR + wsc * 64];
    #pragma unroll
    for (int q = 0; q < 16; ++q) {
      const float4 e4 = *(const float4*)&eb[4 * q];
      epb[4*q+0] = e4.x; epb[4*q+1] = e4.y; epb[4*q+2] = e4.z; epb[4*q+3] = e4.w;
    }
  }

  float zv = (lane < NY) ? (1.0f / NY) : 0.0f;     // z one entry/lane, replicated per wave
  float cc = 0.0f;                                 // c, wave-uniform (bitwise identical)

  #pragma unroll 1
  for (int it = 0; it < NITER; ++it) {
    // ---- P0 (local): full forward dot; key; wave max+ties; segmented candidate compaction ----
    const unsigned long long thk = th_key;         // written post-B1 prev iter -> B2 fences WAR
    float a0 = 0.f, a1 = 0.f, a2 = 0.f, a3 = 0.f;
    #pragma unroll
    for (int j = 0; j < 48; j += 4) {
      a0 = fmaf(er[j + 0], rl_f(zv, j + 0), a0);
      a1 = fmaf(er[j + 1], rl_f(zv, j + 1), a1);
      a2 = fmaf(er[j + 2], rl_f(zv, j + 2), a2);
      a3 = fmaf(er[j + 3], rl_f(zv, j + 3), a3);
    }
    a0 = fmaf(er[48], rl_f(zv, 48), a0);
    a1 = fmaf(er[49], rl_f(zv, 49), a1);
    const float u = ((a0 + a2) + (a1 + a3)) - cc;
    const float r = u * u;
    const unsigned long long key =
        ((unsigned long long)(unsigned)__float_as_int(r) << 32) | (unsigned)tid;
    rrk[tid] = key;                                // fallback scan source

    float m = r;
    DPP_MAXSTEP(m, 0x111); DPP_MAXSTEP(m, 0x112);
    DPP_MAXSTEP(m, 0x114); DPP_MAXSTEP(m, 0x118);
    DPP_MAXSTEP(m, 0x142); DPP_MAXSTEP(m, 0x143);
    const float mw = rl_f(m, 63);                  // wave max, broadcast
    const int   wt = __popcll(__ballot(r == mw));  // wave tie count (ties vs wave max)

    const bool cond = (key <= thk);                // u64-key test: C = THRANK+1 when stable
    const unsigned long long cmask = __ballot(cond);
    const unsigned long long lml   = (1ull << lane) - 1ull;
    const int cpos = __popcll(cmask & lml);
    const int cq   = __popcll(cmask);
    if (cond && cpos < 32) ckey[wsc * 32 + cpos] = key;   // own 32-slot segment
    // pad segment to a multiple of 4 with sentinels so the scan can run 4-unrolled groups
    const int padc  = (0 - cq) & 3;
    const int ncpos = __popcll(~cmask & lml);
    if (!cond && ncpos < padc && (cq + ncpos) < 32) ckey[wsc * 32 + cq + ncpos] = ~0ull;
    if (lane == 0) { wmax4[wsc] = mw; ccnt4[wsc] = cq; wtie4[wsc] = wt; }
    __syncthreads();                               // B1: ckey + {max,tie,count} + rrk

    // ---- P1: global max/ties; exact rank via in-thread scan of segmented candidates; bwd ----
    const float4 wm  = *(const float4*)wmax4;
    const int4   cn  = *(const int4*)ccnt4;
    const int4   wtv = *(const int4*)wtie4;
    const float mx = fmaxf(fmaxf(wm.x, wm.y), fmaxf(wm.z, wm.w));
    const int   cm = (wm.x == mx ? wtv.x : 0) + (wm.y == mx ? wtv.y : 0)
                   + (wm.z == mx ? wtv.z : 0) + (wm.w == mx ? wtv.w : 0);
    const bool ismax = (r == mx);

    const int c0u = __builtin_amdgcn_readfirstlane(cn.x);  // scalarize -> uniform loops
    const int c1u = __builtin_amdgcn_readfirstlane(cn.y);
    const int c2u = __builtin_amdgcn_readfirstlane(cn.z);
    const int c3u = __builtin_amdgcn_readfirstlane(cn.w);
    const int C = (c0u + c1u) + (c2u + c3u);
    const bool valid = ((float)C >= a256) &&
        (c0u <= 32) && (c1u <= 32) && (c2u <= 32) && (c3u <= 32);

    int cnt;
    if (__builtin_expect(valid, 1)) {
      // candidate set = all keys <= thk = exactly the C globally-smallest keys (downward closed)
      // -> rank among candidates == exact global rank for candidates; == C for non-candidates.
      const unsigned long long ck0 = ckey[lane];        // slots 0..63  (quarters 0,1)
      const unsigned long long ck1 = ckey[64 + lane];   // slots 64..127 (quarters 2,3)
      const int g0 = (c0u + 3) >> 2, g1 = (c1u + 3) >> 2;
      const int g2 = (c2u + 3) >> 2, g3 = (c3u + 3) >> 2;
      int n0 = 0, n1 = 0, n2 = 0, n3 = 0;
      #pragma unroll 1
      for (int s = 0; s < g0; ++s) {
        const int b = 4 * s;
        n0 += (rl_u64(ck0, b + 0) < key) ? 1 : 0;
        n1 += (rl_u64(ck0, b + 1) < key) ? 1 : 0;
        n0 += (rl_u64(ck0, b + 2) < key) ? 1 : 0;
        n1 += (rl_u64(ck0, b + 3) < key) ? 1 : 0;
      }
      #pragma unroll 1
      for (int s = 0; s < g1; ++s) {
        const int b = 32 + 4 * s;
        n2 += (rl_u64(ck0, b + 0) < key) ? 1 : 0;
        n3 += (rl_u64(ck0, b + 1) < key) ? 1 : 0;
        n2 += (rl_u64(ck0, b + 2) < key) ? 1 : 0;
        n3 += (rl_u64(ck0, b + 3) < key) ? 1 : 0;
      }
      #pragma unroll 1
      for (int s = 0; s < g2; ++s) {
        const int b = 4 * s;
        n0 += (rl_u64(ck1, b + 0) < key) ? 1 : 0;
        n1 += (rl_u64(ck1, b + 1) < key) ? 1 : 0;
        n0 += (rl_u64(ck1, b + 2) < key) ? 1 : 0;
        n1 += (rl_u64(ck1, b + 3) < key) ? 1 : 0;
      }
      #pragma unroll 1
      for (int s = 0; s < g3; ++s) {
        const int b = 32 + 4 * s;
        n2 += (rl_u64(ck1, b + 0) < key) ? 1 : 0;
        n3 += (rl_u64(ck1, b + 1) < key) ? 1 : 0;
        n2 += (rl_u64(ck1, b + 2) < key) ? 1 : 0;
        n3 += (rl_u64(ck1, b + 3) < key) ? 1 : 0;
      }
      cnt = (n0 + n1) + (n2 + n3);
    } else {                                       // iter 0 / drift: exact full scan
      const ulonglong2* p = (const ulonglong2*)rrk;
      int nf = 0;
      #pragma unroll 8
      for (int j = 0; j < 128; ++j) {
        const ulonglong2 kk = p[j];
        nf += (kk.x < key) ? 1 : 0;
        nf += (kk.y < key) ? 1 : 0;
      }
      cnt = nf;
    }
    // valid mode: rank-40 candidate exists (C=41) and uniquely refreshes theta every iter
    if (cnt == THRANK && (!valid || cond)) th_key = key;

    const float gfac  = fminf(fmaxf((float)cnt + 1.0f - a256, 0.0f), 1.0f) * (1.0f / 256.0f);
    const float g     = gfac + (ismax ? (a / (float)cm) : 0.0f);
    const float coefv = 2.0f * u * g;

    // backward from epb registers; coef of obs wsc*64+q is in lane q of OWN wave
    float q0 = 0.f, q1 = 0.f, q2 = 0.f, q3 = 0.f;
    #pragma unroll
    for (int q = 0; q < 16; ++q) {
      q0 = fmaf(rl_f(coefv, 4 * q + 0), epb[4 * q + 0], q0);
      q1 = fmaf(rl_f(coefv, 4 * q + 1), epb[4 * q + 1], q1);
      q2 = fmaf(rl_f(coefv, 4 * q + 2), epb[4 * q + 2], q2);
      q3 = fmaf(rl_f(coefv, 4 * q + 3), epb[4 * q + 3], q3);
    }
    red4[wsc * 64 + lane] = (q0 + q2) + (q1 + q3);
    __syncthreads();                               // B2: red4 + th_key

    // ---- P2 (local): gradient step + FULL in-wave simplex projection ----
    const float s4 = (red4[lane] + red4[64 + lane]) + (red4[128 + lane] + red4[192 + lane]);
    cc = cc + LRATE * rl_f(s4, NY);                // gc = -sum(coef); col 50 = ones
    const float gz = s4 - gamma * yhl;
    const float v  = zv - LRATE * gz;

    int ahp = 0; float cs0 = 0.f, cs1 = 0.f;
    #pragma unroll
    for (int j = 0; j < NY; j += 2) {              // 50-step scan, index tie-break (matches ref)
      const float vk0 = rl_f(v, j);
      const bool b0 = (vk0 > v) || (vk0 == v && j > lane);
      ahp += b0 ? 1 : 0;
      cs0 += b0 ? vk0 : 0.0f;
      const float vk1 = rl_f(v, j + 1);
      const bool b1 = (vk1 > v) || (vk1 == v && (j + 1) > lane);
      ahp += b1 ? 1 : 0;
      cs1 += b1 ? vk1 : 0.0f;
    }
    const float csF = (cs0 + cs1) + v - 1.0f;
    const bool pc = (lane < NY) && (v - csF / (float)(ahp + 1) > 0.0f);
    const int rho = __popcll(__ballot(pc));        // >= 1 always
    const unsigned long long bsel = __ballot((lane < NY) && (ahp == rho - 1));
    const int srcl = __ffsll(bsel) - 1;
    const float tau =
        __int_as_float(__builtin_amdgcn_readlane(__float_as_int(csF), srcl)) / (float)rho;
    zv = (lane < NY) ? fmaxf(v - tau, 0.0f) : 0.0f;
  }

  if (tid < NY) out[t * NY + tid] = zv;            // wave 0, lanes 0..49
}

extern "C" void kernel_launch(void* const* d_in, const int* in_sizes, int n_in,
                              void* d_out, int out_size, void* d_ws, size_t ws_size,
                              hipStream_t stream) {
  (void)in_sizes; (void)n_in; (void)d_ws; (void)ws_size; (void)out_size;
  const float* X   = (const float*)d_in[0];
  const float* Y   = (const float*)d_in[1];
  const float* W   = (const float*)d_in[2];
  const float* B   = (const float*)d_in[3];
  const float* DLT = (const float*)d_in[4];
  const float* GMM = (const float*)d_in[5];
  float* out = (float*)d_out;
  hipLaunchKernelGGL(dro_kernel, dim3(NOBS), dim3(256), 0, stream,
                     X, Y, W, B, DLT, GMM, out);
}